// Round 6
// baseline (149.940 us; speedup 1.0000x reference)
//
#include <hip/hip_runtime.h>

// E3Hamiltonian spin projection: fixed 4x4 complex mix over channel dim.
// [B=65536, C=8, nL*nR=169] f32, channels [r0 r1 r2 r3 | i0 i1 i2 i3].
//
// Round-6: wave-private DOUBLE-buffered LDS slabs fed by global_load_lds
// (HBM->LDS direct, no dest VGPRs -> no WAR serialization), counted
// s_waitcnt vmcnt(6) so next-item loads stay in flight across the mix+drain
// of the current item (T3/T4 pattern). Zero s_barriers; 14 waves/CU, each
// with a continuous HBM read stream.

#define PLANE 169
#define CSTRIDE 1352          // floats per item
#define QUADS 338             // float4 per item
#define TAIL 18               // QUADS - 320 lanes in 6th load
#define WPB 2                 // waves per 128-thread block
#define BLOCKS 1792           // 7 blocks/CU * 256 CU (LDS-limited residency)

typedef __attribute__((address_space(1))) const void g_as1;
typedef __attribute__((address_space(3))) void l_as3;

__device__ __forceinline__ void gload16(const void* gp, void* lp) {
    // generic->AS1 is bit-identical; generic LDS addr low 32 bits = LDS offset
    // (CK cast_pointer_to_address_space pattern).
    g_as1* g = (g_as1*)(uintptr_t)gp;
    l_as3* l = (l_as3*)(uint32_t)(uintptr_t)lp;
    __builtin_amdgcn_global_load_lds(g, l, 16, 0, 0);
}

// 6 global_load_lds dwordx4: lds dest = uniform slab base + k*1024, HW adds
// lane*16. Always issues exactly 6 VMEM ops per wave (tail has lanes 0..17
// active -> exec never 0), keeping vmcnt arithmetic uniform.
__device__ __forceinline__ void stage_item(const float4* __restrict__ g,
                                           float4* slab4, int lane) {
    #pragma unroll
    for (int k = 0; k < 5; ++k)
        gload16(g + k * 64 + lane, slab4 + k * 64);
    if (lane < TAIL)
        gload16(g + 320 + lane, slab4 + 320);
}

__global__ __launch_bounds__(128) void spin_proj_kernel(
    const float4* __restrict__ in, float4* __restrict__ out,
    int n_items, int W) {
    __shared__ float lds[WPB * 2 * CSTRIDE];   // 21632 B/block
    const int wave = threadIdx.x >> 6;
    const int lane = threadIdx.x & 63;

    float* cur = lds + wave * 2 * CSTRIDE;
    float* nxt = cur + CSTRIDE;

    int it = blockIdx.x * WPB + wave;
    if (it >= n_items) return;

    stage_item(in + (size_t)it * QUADS, (float4*)cur, lane);   // L(it): 6 ops

    const float sc = 0.70710678118654752440f;

    while (it < n_items) {
        const int nx = it + W;
        if (nx < n_items)
            stage_item(in + (size_t)nx * QUADS, (float4*)nxt, lane); // L(nx): 6 ops

        // Wait for everything except the newest 6 VMEM ops (= L(nx), or the
        // previous drain's stores in the tail) -> L(it) is in LDS; L(nx)
        // stays in flight under the mix+drain below. Never vmcnt(0).
        asm volatile("s_waitcnt vmcnt(6)" ::: "memory");
        __builtin_amdgcn_sched_barrier(0);

        // Mix in place; site j owned by one lane, stride-1 -> conflict-free.
        #pragma unroll
        for (int k = 0; k < 3; ++k) {
            const int j = lane + k * 64;
            if (k < 2 || j < PLANE) {
                float r0 = cur[0*PLANE + j], r1 = cur[1*PLANE + j];
                float r2 = cur[2*PLANE + j], r3 = cur[3*PLANE + j];
                float i0 = cur[4*PLANE + j], i1 = cur[5*PLANE + j];
                float i2 = cur[6*PLANE + j], i3 = cur[7*PLANE + j];
                cur[0*PLANE + j] = (r0 + r2) * sc;   // uu.re
                cur[1*PLANE + j] = (i1 + r3) * sc;   // ud.re
                cur[2*PLANE + j] = (r3 - i1) * sc;   // du.re
                cur[3*PLANE + j] = (r0 - r2) * sc;   // dd.re
                cur[4*PLANE + j] = (i0 + i2) * sc;   // uu.im
                cur[5*PLANE + j] = (i3 - r1) * sc;   // ud.im
                cur[6*PLANE + j] = (r1 + i3) * sc;   // du.im
                cur[7*PLANE + j] = (i0 - i2) * sc;   // dd.im
            }
        }

        // Drain: LDS -> global, coalesced b128. Stores depend on the ds_read
        // data, so those reads complete before the next iteration's
        // global_load_lds can overwrite this slab. Stores count 6 VMEM ops.
        {
            float4* __restrict__ g = out + (size_t)it * QUADS;
            const float4* slab4 = (const float4*)cur;
            #pragma unroll
            for (int k = 0; k < 5; ++k)
                g[lane + k * 64] = slab4[lane + k * 64];
            if (lane < TAIL)
                g[320 + lane] = slab4[320 + lane];
        }

        float* tmp = cur; cur = nxt; nxt = tmp;
        it = nx;
    }
}

extern "C" void kernel_launch(void* const* d_in, const int* in_sizes, int n_in,
                              void* d_out, int out_size, void* d_ws, size_t ws_size,
                              hipStream_t stream) {
    const float4* in = (const float4*)d_in[0];
    float4* out = (float4*)d_out;

    const int n_items = in_sizes[0] / CSTRIDE;   // 65536
    int grid = BLOCKS;
    int max_grid = (n_items + WPB - 1) / WPB;
    if (grid > max_grid) grid = max_grid;
    const int W = grid * WPB;                    // total waves = grid stride

    spin_proj_kernel<<<grid, 128, 0, stream>>>(in, out, n_items, W);
}

// Round 7
// 131.323 us; speedup vs baseline: 1.1418x; 1.1418x over previous
//
#include <hip/hip_runtime.h>

// E3Hamiltonian spin projection: fixed 4x4 complex mix over channel dim.
// [B=65536, C=8, nL*nR=169] f32, channels [r0 r1 r2 r3 | i0 i1 i2 i3].
//
// Round-7: round-3 base (wave-private slab, 28 waves/CU, no s_barrier) with
// the mix FUSED into the drain. Stage via global_load_lds (no VGPR roundtrip),
// one vmcnt(0) wait, then each output float4 is computed directly from LDS
// scalars and stored b128 from registers. Per-item serial phases: 3 -> 2;
// LDS instrs/lane: 60 -> ~42.
//
// Output butterfly per out-channel c: out[c] = x*ca + y*cb with
//   x = in[A(c)], y = in[B(c)],  A = {0,3,3,0,4,1,1,4}, B = {2,5,5,2,6,7,7,6}
//   ca = -s only for c=5 (mask 0x20); cb = -s for c in {2,3,7} (mask 0x8C).

#define PLANE 169
#define CSTRIDE 1352          // floats per item
#define QUADS 338             // float4 per item
#define TAIL 18               // quads in the 6th (ragged) stage/drain step
#define WAVES 4               // waves (= items) per 256-thread block

typedef __attribute__((address_space(1))) const void g_as1;
typedef __attribute__((address_space(3))) void l_as3;

__device__ __forceinline__ void gload16(const void* gp, void* lp) {
    g_as1* g = (g_as1*)(uintptr_t)gp;
    l_as3* l = (l_as3*)(uint32_t)(uintptr_t)lp;
    __builtin_amdgcn_global_load_lds(g, l, 16, 0, 0);
}

__global__ __launch_bounds__(256) void spin_proj_kernel(
    const float4* __restrict__ in, float4* __restrict__ out) {
    __shared__ float lds[WAVES * CSTRIDE];   // 21632 B -> 7 blocks/CU, 28 waves
    const int wave = threadIdx.x >> 6;
    const int lane = threadIdx.x & 63;
    float* slab = lds + wave * CSTRIDE;
    float4* slab4 = (float4*)slab;

    const size_t item = (size_t)blockIdx.x * WAVES + wave;

    // Stage: HBM -> LDS direct (6 dwordx4 DMA ops; dest = uniform base + lane*16).
    {
        const float4* __restrict__ g = in + item * QUADS;
        #pragma unroll
        for (int k = 0; k < 5; ++k)
            gload16(g + k * 64 + lane, slab4 + k * 64);
        if (lane < TAIL)
            gload16(g + 320 + lane, slab4 + 320);
    }
    asm volatile("s_waitcnt vmcnt(0)" ::: "memory");
    __builtin_amdgcn_sched_barrier(0);
    __builtin_amdgcn_wave_barrier();

    // Fused mix+drain: compute each output float4 from LDS scalars, store b128.
    float4* __restrict__ gout = out + item * QUADS;
    #pragma unroll
    for (int k = 0; k < 6; ++k) {
        const int q = lane + k * 64;
        if (k == 5 && lane >= TAIL) break;
        const int idx0 = 4 * q;
        const int c0 = idx0 / PLANE;          // magic-mul div by constant
        const int j0 = idx0 - c0 * PLANE;

        float4 o;
        #pragma unroll
        for (int e = 0; e < 4; ++e) {
            int c = c0, j = j0 + e;
            if (j >= PLANE) { c = c0 + 1; j -= PLANE; }   // chunk straddle
            const int A = (0x41140330u >> (c * 4)) & 0xF;
            const int Bc = (0x67762552u >> (c * 4)) & 0xF;
            const unsigned ca_bits = 0x3F3504F3u | (((0x20u >> c) & 1u) << 31);
            const unsigned cb_bits = 0x3F3504F3u | (((0x8Cu >> c) & 1u) << 31);
            const float x = slab[A * PLANE + j];
            const float y = slab[Bc * PLANE + j];
            const float ca = __builtin_bit_cast(float, ca_bits);
            const float cb = __builtin_bit_cast(float, cb_bits);
            float v = x * ca;
            v = fmaf(y, cb, v);
            if (e == 0) o.x = v; else if (e == 1) o.y = v;
            else if (e == 2) o.z = v; else o.w = v;
        }
        gout[q] = o;   // 16B-aligned, coalesced across lanes
    }
}

extern "C" void kernel_launch(void* const* d_in, const int* in_sizes, int n_in,
                              void* d_out, int out_size, void* d_ws, size_t ws_size,
                              hipStream_t stream) {
    const float4* in = (const float4*)d_in[0];
    float4* out = (float4*)d_out;

    const int n_items = in_sizes[0] / CSTRIDE;   // 65536
    const int grid = n_items / WAVES;            // 16384 blocks
    spin_proj_kernel<<<grid, 256, 0, stream>>>(in, out);
}